// Round 2
// baseline (180.603 us; speedup 1.0000x reference)
//
#include <hip/hip_runtime.h>
#include <stdint.h>

// HierarchicalZ2_12Quantizer on MI355X (gfx950) — two-kernel version.
// tokens = 8*4096 = 32768, D = 1024
// Kernel A: x @ W24 via bf16 MFMA -> soft-quantize -> gate-scaled V (bf16) to ws.
// Kernel B: V @ Wf via bf16 MFMA, chunked LDS epilogue, out = x + corr (coalesced).
// codes derived from bit patterns: c[j][i] = ((j>>(n-1-i))&1)?+1:-1.

#define DM 1024
#define MTA 64
#define OUT_OFF ((size_t)33554432)  // 8*4096*1024
#define NTOK 32768

typedef float f32x4 __attribute__((ext_vector_type(4)));
typedef short bf16x8 __attribute__((ext_vector_type(8)));

__device__ __forceinline__ short f2bf(float f){
  unsigned u = __builtin_bit_cast(unsigned, f);
  unsigned r = u + 0x7fffu + ((u >> 16) & 1u);   // round-to-nearest-even
  return (short)(r >> 16);
}

// soft_quantize over the 2^NB hypercube corners; z[NB] -> q[NB]
template<int NB>
__device__ __forceinline__ void softq(const float* z, float invt, float* q){
  constexpr int K = 1 << NB;
  float d[K];
  float dmin = 3.4e38f;
#pragma unroll
  for (int j = 0; j < K; ++j){
    float acc = 0.f;
#pragma unroll
    for (int i = 0; i < NB; ++i){
      float c = ((j >> (NB-1-i)) & 1) ? 1.f : -1.f;
      float t = z[i] - c;
      acc = fmaf(t, t, acc);
    }
    float dj = sqrtf(acc);
    d[j] = dj;
    dmin = fminf(dmin, dj);
  }
  float S = 0.f;
  float s1[NB];
#pragma unroll
  for (int i = 0; i < NB; ++i) s1[i] = 0.f;
#pragma unroll
  for (int j = 0; j < K; ++j){
    float wj = __expf((dmin - d[j]) * invt);
    S += wj;
#pragma unroll
    for (int i = 0; i < NB; ++i)
      if ((j >> (NB-1-i)) & 1) s1[i] += wj;   // compile-time bit -> no branch
  }
  float rS = 1.f / S;
#pragma unroll
  for (int i = 0; i < NB; ++i) q[i] = 2.f * s1[i] * rS - 1.f;  // (S1-S0)/S
}

// ---------------- Kernel A: down-proj + quantize -> wsV (bf16, stride 32) ---
__global__ __launch_bounds__(256) void down_kernel(
    const float* __restrict__ x,
    const float* __restrict__ w_to_l1,  const float* __restrict__ w_to_l2,
    const float* __restrict__ w_to_l3u, const float* __restrict__ w_to_l3l,
    const float* __restrict__ w_gate,   const float* __restrict__ b_gate,
    const float* __restrict__ t1p, const float* __restrict__ t2p, const float* __restrict__ t3p,
    const float* __restrict__ s1p, const float* __restrict__ s2p, const float* __restrict__ s3p,
    short* __restrict__ wsV, float* __restrict__ out)
{
  __shared__ alignas(16) short WF[32768];   // W24 B-fragments (64 KB); aliased by V64s later
  __shared__ float P [MTA*33];              // down-proj result, padded rows
  __shared__ float GS[MTA*3];               // gate*scale per token

  short* V64s = (short*)WF;                 // [64][32] bf16, alias (WF dead after down-proj)

  const int tid  = threadIdx.x;
  const int l    = tid & 63;
  const int wv   = tid >> 6;    // wave 0..3, owns tokens [16*wv, 16*wv+16)
  const int kg   = l >> 4;
  const int ln16 = l & 15;
  const int tb   = blockIdx.x * MTA;

  // stage W24 B-fragments: B[k][n], lane: n=nf*16+(l&15), k=32s+kg*8+j
  for (int e = tid; e < 32768; e += 256){
    int s  = e >> 10;
    int nf = (e >> 9) & 1;
    int ll = (e >> 3) & 63;
    int j  = e & 7;
    int k  = s*32 + ((ll >> 4) << 3) + j;
    int n  = nf*16 + (ll & 15);
    float v;
    if      (n < 3)  v = w_gate  [k*3 + n];
    else if (n < 6)  v = w_to_l1 [k*3 + (n-3)];
    else if (n < 12) v = w_to_l2 [k*6 + (n-6)];
    else if (n < 18) v = w_to_l3u[k*6 + (n-12)];
    else if (n < 24) v = w_to_l3l[k*6 + (n-18)];
    else             v = 0.f;
    WF[e] = f2bf(v);
  }
  __syncthreads();

  // down-proj: P[tok][0:24] = x @ W24  (cols: gate0..2, z1 x3, z2 x6, z3u x6, z3l x6)
  {
    f32x4 acc0 = {0.f,0.f,0.f,0.f}, acc1 = {0.f,0.f,0.f,0.f};
    const float4* xp = reinterpret_cast<const float4*>(
        x + (size_t)(tb + wv*16 + ln16)*DM + kg*8);
#pragma unroll
    for (int su = 0; su < 32; su += 8){
      float4 a0[8], a1[8];
#pragma unroll
      for (int u = 0; u < 8; ++u){ a0[u] = xp[(su+u)*8]; a1[u] = xp[(su+u)*8 + 1]; }
#pragma unroll
      for (int u = 0; u < 8; ++u){
        int s = su + u;
        bf16x8 af;
        af[0]=f2bf(a0[u].x); af[1]=f2bf(a0[u].y); af[2]=f2bf(a0[u].z); af[3]=f2bf(a0[u].w);
        af[4]=f2bf(a1[u].x); af[5]=f2bf(a1[u].y); af[6]=f2bf(a1[u].z); af[7]=f2bf(a1[u].w);
        bf16x8 b0 = *reinterpret_cast<const bf16x8*>(&WF[(s*2+0)*512 + l*8]);
        bf16x8 b1 = *reinterpret_cast<const bf16x8*>(&WF[(s*2+1)*512 + l*8]);
        acc0 = __builtin_amdgcn_mfma_f32_16x16x32_bf16(af, b0, acc0, 0, 0, 0);
        acc1 = __builtin_amdgcn_mfma_f32_16x16x32_bf16(af, b1, acc1, 0, 0, 0);
      }
    }
#pragma unroll
    for (int r = 0; r < 4; ++r){        // D: col = l&15, row = kg*4 + r
      int lr = wv*16 + kg*4 + r;
      P[lr*33 + ln16]      = acc0[r];
      P[lr*33 + 16 + ln16] = acc1[r];
    }
  }
  __syncthreads();   // P ready; WF no longer read -> V64s alias safe

  // quantize: one token per thread, one role per wave (0:l2 1:l3u 2:l3l 3:gate+l1)
  {
    const int grp = wv;
    const int t   = l;          // token index within block
    float qv[6] = {0,0,0,0,0,0};
    float myscale = 0.f;
    if (grp == 3){
      float invt1 = 1.f / fminf(fmaxf(__expf(t1p[0]), 0.01f), 5.0f);
      float g0l = P[t*33+0] + b_gate[0];
      float g1l = P[t*33+1] + b_gate[1];
      float g2l = P[t*33+2] + b_gate[2];
      float m  = fmaxf(g0l, fmaxf(g1l, g2l));
      float e0 = __expf(g0l - m), e1 = __expf(g1l - m), e2 = __expf(g2l - m);
      float rs = 1.f / (e0 + e1 + e2);
      float g0 = e0*rs, g1 = e1*rs, g2 = e2*rs;
      GS[t*3+0] = g0 * s1p[0];
      GS[t*3+1] = g1 * s2p[0];
      GS[t*3+2] = g2 * s3p[0];
      myscale   = g0 * s1p[0];
      float z1[3] = {P[t*33+3], P[t*33+4], P[t*33+5]};
      softq<3>(z1, invt1, qv);
      // gate means: wave reduce + atomic (zeroed by zero_gate_kernel each launch)
      float sg0=g0, sg1=g1, sg2=g2;
#pragma unroll
      for (int mm = 1; mm < 64; mm <<= 1){
        sg0 += __shfl_xor(sg0, mm, 64);
        sg1 += __shfl_xor(sg1, mm, 64);
        sg2 += __shfl_xor(sg2, mm, 64);
      }
      if (l == 0){
        const float sc = 1.f / (float)NTOK;
        atomicAdd(out + OUT_OFF + 0, sg0 * sc);
        atomicAdd(out + OUT_OFF + 1, sg1 * sc);
        atomicAdd(out + OUT_OFF + 2, sg2 * sc);
      }
    } else {
      float tl = (grp == 0) ? t2p[0] : t3p[0];
      float invt = 1.f / fminf(fmaxf(__expf(tl), 0.01f), 5.0f);
      float z[6];
#pragma unroll
      for (int i = 0; i < 6; ++i) z[i] = P[t*33 + 6 + grp*6 + i];
      softq<6>(z, invt, qv);
    }
    __syncthreads();   // GS visible; WF reads done everywhere
    if (grp == 3){
#pragma unroll
      for (int i = 0; i < 3; ++i) V64s[t*32 + i] = f2bf(myscale * qv[i]);
#pragma unroll
      for (int i = 21; i < 32; ++i) V64s[t*32 + i] = 0;
    } else {
      float sc = GS[t*3 + ((grp == 0) ? 1 : 2)];
      int voff = 3 + grp*6;   // l2 -> 3..8, l3u -> 9..14, l3l -> 15..20
#pragma unroll
      for (int i = 0; i < 6; ++i) V64s[t*32 + voff + i] = f2bf(sc * qv[i]);
    }
  }
  __syncthreads();

  // copy V64s -> wsV, coalesced 16B per thread
  {
    int row = tid >> 2, seg = tid & 3;
    bf16x8 v = *reinterpret_cast<const bf16x8*>(&V64s[row*32 + seg*8]);
    *reinterpret_cast<bf16x8*>(&wsV[(size_t)(tb + row)*32 + seg*8]) = v;
  }
}

// ---------------- Kernel B: up-proj + residual (chunked coalesced epilogue) --
__global__ __launch_bounds__(256) void up_kernel(
    const short* __restrict__ wsV, const float* __restrict__ x,
    const float* __restrict__ w_from_l1, const float* __restrict__ w_from_l2,
    const float* __restrict__ w_from_l3, float* __restrict__ out)
{
  __shared__ alignas(16) short WFC[24576];  // compact Wf frags: 64 frags x 48 lanes x 8 (48 KB)
  __shared__ float C[MTA*68];               // corr chunk [64][68], stride 68 (17.4 KB)

  const int tid  = threadIdx.x;
  const int l    = tid & 63;
  const int wv   = tid >> 6;
  const int kg   = l >> 4;
  const int ln16 = l & 15;
  const int tb   = blockIdx.x * MTA;

  // stage compact Wf B-fragments: B[k][d], only kg<3 lanes (k<24; k>=21 zero)
  for (int e = tid; e < 24576; e += 256){
    int f   = e / 384;
    int rem = e - f*384;
    int ll  = rem >> 3;
    int j   = e & 7;
    int k   = ((ll >> 4) << 3) + j;      // 0..23
    int dd  = f*16 + (ll & 15);
    float v;
    if      (k < 3)  v = w_from_l1[k*DM + dd];
    else if (k < 9)  v = w_from_l2[(k-3)*DM + dd];
    else if (k < 21) v = w_from_l3[(k-9)*DM + dd];
    else             v = 0.f;
    WFC[e] = f2bf(v);
  }

  // A-fragment: V row slice straight from ws (independent of LDS)
  bf16x8 aV = {0,0,0,0,0,0,0,0};
  if (kg < 3)
    aV = *reinterpret_cast<const bf16x8*>(&wsV[(size_t)(tb + wv*16 + ln16)*32 + kg*8]);
  __syncthreads();

  const f32x4 z4 = {0.f,0.f,0.f,0.f};
  const int rrow = tid >> 4;        // 0..15
  const int rcol = (tid & 15) * 4;  // 0..60

#pragma unroll 1
  for (int c = 0; c < 16; ++c){
    // issue x loads for this chunk early (hide L3 latency under MFMA phase)
    float4 xv[4];
#pragma unroll
    for (int p = 0; p < 4; ++p){
      int row = p*16 + rrow;
      xv[p] = *reinterpret_cast<const float4*>(&x[(size_t)(tb + row)*DM + c*64 + rcol]);
    }
    // compute 64-col chunk: 4 MFMA, write corr to LDS
#pragma unroll
    for (int ff = 0; ff < 4; ++ff){
      bf16x8 bfr = {0,0,0,0,0,0,0,0};
      if (kg < 3)
        bfr = *reinterpret_cast<const bf16x8*>(&WFC[(c*4+ff)*384 + l*8]);
      f32x4 dd = __builtin_amdgcn_mfma_f32_16x16x32_bf16(aV, bfr, z4, 0, 0, 0);
#pragma unroll
      for (int r = 0; r < 4; ++r)
        C[(wv*16 + kg*4 + r)*68 + ff*16 + ln16] = dd[r];
    }
    __syncthreads();
    // coalesced add pass: out = x + corr, float4 per thread per row-pass
#pragma unroll
    for (int p = 0; p < 4; ++p){
      int row = p*16 + rrow;
      float4 cv = *reinterpret_cast<const float4*>(&C[row*68 + rcol]);
      float4 ov;
      ov.x = xv[p].x + cv.x; ov.y = xv[p].y + cv.y;
      ov.z = xv[p].z + cv.z; ov.w = xv[p].w + cv.w;
      *reinterpret_cast<float4*>(&out[(size_t)(tb + row)*DM + c*64 + rcol]) = ov;
    }
    __syncthreads();
  }
}

__global__ void zero_gate_kernel(float* out){
  if (threadIdx.x < 3) out[OUT_OFF + threadIdx.x] = 0.f;
}

extern "C" void kernel_launch(void* const* d_in, const int* in_sizes, int n_in,
                              void* d_out, int out_size, void* d_ws, size_t ws_size,
                              hipStream_t stream){
  (void)in_sizes; (void)n_in; (void)ws_size; (void)out_size;
  const float* x         = (const float*)d_in[0];
  // d_in[1] (codes_l1), d_in[2] (codes_l2) unused: corners derived from bits
  const float* w_to_l1   = (const float*)d_in[3];
  const float* w_from_l1 = (const float*)d_in[4];
  const float* w_to_l2   = (const float*)d_in[5];
  const float* w_from_l2 = (const float*)d_in[6];
  const float* w_to_l3u  = (const float*)d_in[7];
  const float* w_to_l3l  = (const float*)d_in[8];
  const float* w_from_l3 = (const float*)d_in[9];
  const float* w_gate    = (const float*)d_in[10];
  const float* b_gate    = (const float*)d_in[11];
  const float* t1 = (const float*)d_in[12];
  const float* t2 = (const float*)d_in[13];
  const float* t3 = (const float*)d_in[14];
  const float* s1 = (const float*)d_in[15];
  const float* s2 = (const float*)d_in[16];
  const float* s3 = (const float*)d_in[17];
  float* out  = (float*)d_out;
  short* wsV  = (short*)d_ws;   // 32768 x 32 bf16 = 2 MB

  zero_gate_kernel<<<dim3(1), dim3(64), 0, stream>>>(out);
  down_kernel<<<dim3(512), dim3(256), 0, stream>>>(
      x, w_to_l1, w_to_l2, w_to_l3u, w_to_l3l, w_gate, b_gate,
      t1, t2, t3, s1, s2, s3, wsV, out);
  up_kernel<<<dim3(512), dim3(256), 0, stream>>>(
      wsV, x, w_from_l1, w_from_l2, w_from_l3, out);
}

// Round 3
// 106.013 us; speedup vs baseline: 1.7036x; 1.7036x over previous
//
#include <hip/hip_runtime.h>
#include <stdint.h>

// HierarchicalZ2_12Quantizer on MI355X (gfx950) — three-kernel version.
// tokens = 8*4096 = 32768, D = 1024
// pack_kernel: gather weights ONCE into bf16 MFMA B-fragments in ws
//              (R2 post-mortem: per-block gathers = 16.7M scalar L2 txns = 167us).
// down_kernel: x @ W24 via bf16 MFMA (frags read coalesced from ws/L2),
//              soft-quantize, gate-scaled V (bf16) -> ws.
// up_kernel:   V @ Wf via bf16 MFMA, chunked LDS epilogue, out = x + corr.
// codes derived from bit patterns: c[j][i] = ((j>>(n-1-i))&1)?+1:-1.

#define DM 1024
#define MTA 64
#define OUT_OFF ((size_t)33554432)  // 8*4096*1024
#define NTOK 32768
#define WSV_OFF 65536               // short offset of V buffer in ws

typedef float f32x4 __attribute__((ext_vector_type(4)));
typedef short bf16x8 __attribute__((ext_vector_type(8)));

__device__ __forceinline__ short f2bf(float f){
  unsigned u = __builtin_bit_cast(unsigned, f);
  unsigned r = u + 0x7fffu + ((u >> 16) & 1u);   // round-to-nearest-even
  return (short)(r >> 16);
}

// soft_quantize over the 2^NB hypercube corners; z[NB] -> q[NB]
template<int NB>
__device__ __forceinline__ void softq(const float* z, float invt, float* q){
  constexpr int K = 1 << NB;
  float d[K];
  float dmin = 3.4e38f;
#pragma unroll
  for (int j = 0; j < K; ++j){
    float acc = 0.f;
#pragma unroll
    for (int i = 0; i < NB; ++i){
      float c = ((j >> (NB-1-i)) & 1) ? 1.f : -1.f;
      float t = z[i] - c;
      acc = fmaf(t, t, acc);
    }
    float dj = sqrtf(acc);
    d[j] = dj;
    dmin = fminf(dmin, dj);
  }
  float S = 0.f;
  float s1[NB];
#pragma unroll
  for (int i = 0; i < NB; ++i) s1[i] = 0.f;
#pragma unroll
  for (int j = 0; j < K; ++j){
    float wj = __expf((dmin - d[j]) * invt);
    S += wj;
#pragma unroll
    for (int i = 0; i < NB; ++i)
      if ((j >> (NB-1-i)) & 1) s1[i] += wj;   // compile-time bit -> no branch
  }
  float rS = 1.f / S;
#pragma unroll
  for (int i = 0; i < NB; ++i) q[i] = 2.f * s1[i] * rS - 1.f;  // (S1-S0)/S
}

// ---------------- pack: weights -> bf16 B-fragments in ws (once) ------------
// wsF[0..32768)      : W24 frags, 32 ksteps x 2 nfrags x 64 lanes x 8
// wsF[32768..57344)  : Wf compact frags, 64 dfrags x 48 lanes x 8 (k<24)
__global__ __launch_bounds__(256) void pack_kernel(
    const float* __restrict__ w_to_l1,  const float* __restrict__ w_to_l2,
    const float* __restrict__ w_to_l3u, const float* __restrict__ w_to_l3l,
    const float* __restrict__ w_gate,
    const float* __restrict__ w_from_l1, const float* __restrict__ w_from_l2,
    const float* __restrict__ w_from_l3,
    short* __restrict__ wsF, float* __restrict__ out)
{
  int base = blockIdx.x*4096 + threadIdx.x*16;
#pragma unroll
  for (int q = 0; q < 16; ++q){
    int e = base + q;
    float v;
    if (e < 32768){
      int s  = e >> 10;
      int nf = (e >> 9) & 1;
      int ll = (e >> 3) & 63;
      int j  = e & 7;
      int k  = s*32 + ((ll >> 4) << 3) + j;
      int n  = nf*16 + (ll & 15);
      if      (n < 3)  v = w_gate  [k*3 + n];
      else if (n < 6)  v = w_to_l1 [k*3 + (n-3)];
      else if (n < 12) v = w_to_l2 [k*6 + (n-6)];
      else if (n < 18) v = w_to_l3u[k*6 + (n-12)];
      else if (n < 24) v = w_to_l3l[k*6 + (n-18)];
      else             v = 0.f;
    } else {
      int e2  = e - 32768;
      int f   = e2 / 384;
      int rem = e2 - f*384;
      int ll  = rem >> 3;
      int j   = e2 & 7;
      int k   = ((ll >> 4) << 3) + j;      // 0..23
      int dd  = f*16 + (ll & 15);
      if      (k < 3)  v = w_from_l1[k*DM + dd];
      else if (k < 9)  v = w_from_l2[(k-3)*DM + dd];
      else if (k < 21) v = w_from_l3[(k-9)*DM + dd];
      else             v = 0.f;
    }
    wsF[e] = f2bf(v);
  }
  if (blockIdx.x == 0 && threadIdx.x < 3) out[OUT_OFF + threadIdx.x] = 0.f;
}

// ---------------- down-proj + quantize -> wsV (bf16, stride 32) -------------
__global__ __launch_bounds__(256) void down_kernel(
    const float* __restrict__ x, const short* __restrict__ wsF,
    const float* __restrict__ b_gate,
    const float* __restrict__ t1p, const float* __restrict__ t2p, const float* __restrict__ t3p,
    const float* __restrict__ s1p, const float* __restrict__ s2p, const float* __restrict__ s3p,
    short* __restrict__ wsV, float* __restrict__ out)
{
  __shared__ float P [MTA*33];              // down-proj result, padded rows (8.4 KB)
  __shared__ float GS[MTA*3];               // gate*scale per token
  __shared__ short V64s[MTA*32];            // quantized V staging (4 KB)

  const int tid  = threadIdx.x;
  const int l    = tid & 63;
  const int wv   = tid >> 6;    // wave 0..3, owns tokens [16*wv, 16*wv+16)
  const int kg   = l >> 4;
  const int ln16 = l & 15;
  const int tb   = blockIdx.x * MTA;

  // down-proj: P[tok][0:24] = x @ W24  (cols: gate0..2, z1 x3, z2 x6, z3u x6, z3l x6)
  // B-fragments read straight from ws (coalesced 1KB wave-reads, L2-resident).
  {
    f32x4 acc0 = {0.f,0.f,0.f,0.f}, acc1 = {0.f,0.f,0.f,0.f};
    const float4* xp = reinterpret_cast<const float4*>(
        x + (size_t)(tb + wv*16 + ln16)*DM + kg*8);
#pragma unroll
    for (int su = 0; su < 32; su += 8){
      float4 a0[8], a1[8];
#pragma unroll
      for (int u = 0; u < 8; ++u){ a0[u] = xp[(su+u)*8]; a1[u] = xp[(su+u)*8 + 1]; }
#pragma unroll
      for (int u = 0; u < 8; ++u){
        int s = su + u;
        bf16x8 af;
        af[0]=f2bf(a0[u].x); af[1]=f2bf(a0[u].y); af[2]=f2bf(a0[u].z); af[3]=f2bf(a0[u].w);
        af[4]=f2bf(a1[u].x); af[5]=f2bf(a1[u].y); af[6]=f2bf(a1[u].z); af[7]=f2bf(a1[u].w);
        bf16x8 b0 = *reinterpret_cast<const bf16x8*>(&wsF[(s*2+0)*512 + l*8]);
        bf16x8 b1 = *reinterpret_cast<const bf16x8*>(&wsF[(s*2+1)*512 + l*8]);
        acc0 = __builtin_amdgcn_mfma_f32_16x16x32_bf16(af, b0, acc0, 0, 0, 0);
        acc1 = __builtin_amdgcn_mfma_f32_16x16x32_bf16(af, b1, acc1, 0, 0, 0);
      }
    }
#pragma unroll
    for (int r = 0; r < 4; ++r){        // D: col = l&15, row = kg*4 + r
      int lr = wv*16 + kg*4 + r;
      P[lr*33 + ln16]      = acc0[r];
      P[lr*33 + 16 + ln16] = acc1[r];
    }
  }
  __syncthreads();   // P ready

  // quantize: one token per thread, one role per wave (0:l2 1:l3u 2:l3l 3:gate+l1)
  {
    const int grp = wv;
    const int t   = l;          // token index within block
    float qv[6] = {0,0,0,0,0,0};
    float myscale = 0.f;
    if (grp == 3){
      float invt1 = 1.f / fminf(fmaxf(__expf(t1p[0]), 0.01f), 5.0f);
      float g0l = P[t*33+0] + b_gate[0];
      float g1l = P[t*33+1] + b_gate[1];
      float g2l = P[t*33+2] + b_gate[2];
      float m  = fmaxf(g0l, fmaxf(g1l, g2l));
      float e0 = __expf(g0l - m), e1 = __expf(g1l - m), e2 = __expf(g2l - m);
      float rs = 1.f / (e0 + e1 + e2);
      float g0 = e0*rs, g1 = e1*rs, g2 = e2*rs;
      GS[t*3+0] = g0 * s1p[0];
      GS[t*3+1] = g1 * s2p[0];
      GS[t*3+2] = g2 * s3p[0];
      myscale   = g0 * s1p[0];
      float z1[3] = {P[t*33+3], P[t*33+4], P[t*33+5]};
      softq<3>(z1, invt1, qv);
      // gate means: wave reduce + atomic (zeroed by pack_kernel each launch)
      float sg0=g0, sg1=g1, sg2=g2;
#pragma unroll
      for (int mm = 1; mm < 64; mm <<= 1){
        sg0 += __shfl_xor(sg0, mm, 64);
        sg1 += __shfl_xor(sg1, mm, 64);
        sg2 += __shfl_xor(sg2, mm, 64);
      }
      if (l == 0){
        const float sc = 1.f / (float)NTOK;
        atomicAdd(out + OUT_OFF + 0, sg0 * sc);
        atomicAdd(out + OUT_OFF + 1, sg1 * sc);
        atomicAdd(out + OUT_OFF + 2, sg2 * sc);
      }
    } else {
      float tl = (grp == 0) ? t2p[0] : t3p[0];
      float invt = 1.f / fminf(fmaxf(__expf(tl), 0.01f), 5.0f);
      float z[6];
#pragma unroll
      for (int i = 0; i < 6; ++i) z[i] = P[t*33 + 6 + grp*6 + i];
      softq<6>(z, invt, qv);
    }
    __syncthreads();   // GS visible to all waves
    if (grp == 3){
#pragma unroll
      for (int i = 0; i < 3; ++i) V64s[t*32 + i] = f2bf(myscale * qv[i]);
#pragma unroll
      for (int i = 21; i < 32; ++i) V64s[t*32 + i] = 0;
    } else {
      float sc = GS[t*3 + ((grp == 0) ? 1 : 2)];
      int voff = 3 + grp*6;   // l2 -> 3..8, l3u -> 9..14, l3l -> 15..20
#pragma unroll
      for (int i = 0; i < 6; ++i) V64s[t*32 + voff + i] = f2bf(sc * qv[i]);
    }
  }
  __syncthreads();

  // copy V64s -> wsV, coalesced 16B per thread
  {
    int row = tid >> 2, seg = tid & 3;
    bf16x8 v = *reinterpret_cast<const bf16x8*>(&V64s[row*32 + seg*8]);
    *reinterpret_cast<bf16x8*>(&wsV[(size_t)(tb + row)*32 + seg*8]) = v;
  }
}

// ---------------- up-proj + residual (chunked coalesced epilogue) -----------
__global__ __launch_bounds__(256) void up_kernel(
    const short* __restrict__ wsF, const short* __restrict__ wsV,
    const float* __restrict__ x, float* __restrict__ out)
{
  __shared__ float C[MTA*68];               // corr chunk [64][68], stride 68 (17.4 KB)

  const int tid  = threadIdx.x;
  const int l    = tid & 63;
  const int wv   = tid >> 6;
  const int kg   = l >> 4;
  const int ln16 = l & 15;
  const int tb   = blockIdx.x * MTA;
  const short* wsFC = wsF + 32768;          // compact Wf frags

  // A-fragment: V row slice straight from ws
  bf16x8 aV = {0,0,0,0,0,0,0,0};
  if (kg < 3)
    aV = *reinterpret_cast<const bf16x8*>(&wsV[(size_t)(tb + wv*16 + ln16)*32 + kg*8]);

  const f32x4 z4 = {0.f,0.f,0.f,0.f};
  const int rrow = tid >> 4;        // 0..15
  const int rcol = (tid & 15) * 4;  // 0..60

#pragma unroll 1
  for (int c = 0; c < 16; ++c){
    // issue x loads for this chunk early (hide latency under MFMA phase)
    float4 xv[4];
#pragma unroll
    for (int p = 0; p < 4; ++p){
      int row = p*16 + rrow;
      xv[p] = *reinterpret_cast<const float4*>(&x[(size_t)(tb + row)*DM + c*64 + rcol]);
    }
    // compute 64-col chunk: 4 MFMA, write corr to LDS
#pragma unroll
    for (int ff = 0; ff < 4; ++ff){
      bf16x8 bfr = {0,0,0,0,0,0,0,0};
      if (kg < 3)
        bfr = *reinterpret_cast<const bf16x8*>(&wsFC[(c*4+ff)*384 + l*8]);
      f32x4 dd = __builtin_amdgcn_mfma_f32_16x16x32_bf16(aV, bfr, z4, 0, 0, 0);
#pragma unroll
      for (int r = 0; r < 4; ++r)
        C[(wv*16 + kg*4 + r)*68 + ff*16 + ln16] = dd[r];
    }
    __syncthreads();
    // coalesced add pass: out = x + corr, float4 per thread per row-pass
#pragma unroll
    for (int p = 0; p < 4; ++p){
      int row = p*16 + rrow;
      float4 cv = *reinterpret_cast<const float4*>(&C[row*68 + rcol]);
      float4 ov;
      ov.x = xv[p].x + cv.x; ov.y = xv[p].y + cv.y;
      ov.z = xv[p].z + cv.z; ov.w = xv[p].w + cv.w;
      *reinterpret_cast<float4*>(&out[(size_t)(tb + row)*DM + c*64 + rcol]) = ov;
    }
    __syncthreads();
  }
}

extern "C" void kernel_launch(void* const* d_in, const int* in_sizes, int n_in,
                              void* d_out, int out_size, void* d_ws, size_t ws_size,
                              hipStream_t stream){
  (void)in_sizes; (void)n_in; (void)ws_size; (void)out_size;
  const float* x         = (const float*)d_in[0];
  // d_in[1] (codes_l1), d_in[2] (codes_l2) unused: corners derived from bits
  const float* w_to_l1   = (const float*)d_in[3];
  const float* w_from_l1 = (const float*)d_in[4];
  const float* w_to_l2   = (const float*)d_in[5];
  const float* w_from_l2 = (const float*)d_in[6];
  const float* w_to_l3u  = (const float*)d_in[7];
  const float* w_to_l3l  = (const float*)d_in[8];
  const float* w_from_l3 = (const float*)d_in[9];
  const float* w_gate    = (const float*)d_in[10];
  const float* b_gate    = (const float*)d_in[11];
  const float* t1 = (const float*)d_in[12];
  const float* t2 = (const float*)d_in[13];
  const float* t3 = (const float*)d_in[14];
  const float* s1 = (const float*)d_in[15];
  const float* s2 = (const float*)d_in[16];
  const float* s3 = (const float*)d_in[17];
  float* out  = (float*)d_out;
  short* wsF  = (short*)d_ws;              // 57344 shorts of packed fragments
  short* wsV  = (short*)d_ws + WSV_OFF;    // 32768 x 32 bf16 = 2 MB

  pack_kernel<<<dim3(14), dim3(256), 0, stream>>>(
      w_to_l1, w_to_l2, w_to_l3u, w_to_l3l, w_gate,
      w_from_l1, w_from_l2, w_from_l3, wsF, out);
  down_kernel<<<dim3(512), dim3(256), 0, stream>>>(
      x, wsF, b_gate, t1, t2, t3, s1, s2, s3, wsV, out);
  up_kernel<<<dim3(512), dim3(256), 0, stream>>>(
      wsF, wsV, x, out);
}